// Round 1
// baseline (236.676 us; speedup 1.0000x reference)
//
#include <hip/hip_runtime.h>
#include <hip/hip_bf16.h>

// y[b, c] = (sum_k x[b,k] * W[c % 512, k]) + bias[c]
// R6: split-K=4 x 128x128-tile GEMM (m97-class structure) replacing the 64x64
// tiles whose 2-barrier structure capped us at ~295 TF (MfmaUtil 11%).
//   - 512 blocks = 32 mt x 4 nt x 4 ksplit, 2 blocks/CU, 256 thr (4 waves),
//     wave tile 64x64 (4x4 frags), BK=64, 2-stage LDS ring (64 KiB total),
//     counted s_waitcnt vmcnt(8) so next tile's DMA stays in flight.
//   - Each split stores its fp32 partial into output replica slot #ks
//     (cols nt*128 + ks*512) -- storage the tile must write anyway.
//   - Per-tile ticket (agent-scope atomicAdd after __threadfence); the
//     last-arriving split reads the 4 slots back (float4, L2/L3-warm),
//     adds bias, broadcasts to all 8 replica slots. No third kernel.
//   - DMA chunk-XOR swizzle + global_load_lds(16B) + fragment layout carried
//     over unchanged from the verified R5 kernel (scaled 2x2 -> 4x4 frags).
//   - XCD swizzle: the 4 nt-blocks of one (mt,ks) x-slab share an XCD.
// Workspace: 32 MiB xb + 4 MiB wb + 512 B tickets (zeroed by convert_kernel).

typedef __bf16 bf8 __attribute__((ext_vector_type(8)));
typedef float f4 __attribute__((ext_vector_type(4)));
typedef unsigned int uint;
typedef unsigned short ushort;

constexpr int M = 4096;
constexpr int K = 4096;
constexpr int NS = 512;
constexpr int OUTF = 4096;

constexpr int BM = 128, BN = 128, BK = 64;
constexpr int SPLITS = 4;
constexpr int KSPL = K / SPLITS;     // 1024
constexpr int NITER = KSPL / BK;     // 16
constexpr int MT = M / BM;           // 32
constexpr int NT = NS / BN;          // 4
constexpr int NTILES = MT * NT;      // 128

#define PERM_HI2(hi, lo) __builtin_amdgcn_perm((hi), (lo), 0x07060302u)
// s_waitcnt imm: vmcnt[3:0]|expcnt[6:4]|lgkmcnt[11:8]|vmcnt[15:14]
#define WAITCNT_VM8 0xF78   // vmcnt<=8 (tile kk landed, tile kk+1 in flight)
#define WAITCNT_VM0 0xF70   // vmcnt<=0

__device__ __forceinline__ void async16(const ushort* g, ushort* l) {
  __builtin_amdgcn_global_load_lds(
      (const __attribute__((address_space(1))) void*)g,
      (__attribute__((address_space(3))) void*)l, 16, 0, 0);
}

// fp32 -> bf16 (truncate), 8 elems/thread; covers x then W exactly.
// Block 0 additionally zeroes the split-K tickets for this launch.
__global__ __launch_bounds__(256)
void convert_kernel(const float* __restrict__ x, const float* __restrict__ w,
                    ushort* __restrict__ xb, ushort* __restrict__ wb,
                    uint* __restrict__ tickets) {
  if (blockIdx.x == 0 && threadIdx.x < NTILES) tickets[threadIdx.x] = 0u;
  const size_t i = (size_t)blockIdx.x * 256 + threadIdx.x;
  constexpr size_t NX = (size_t)M * K / 8;
  const float* src;
  ushort* dst;
  if (i < NX) { src = x + i * 8; dst = xb + i * 8; }
  else        { const size_t j = i - NX; src = w + j * 8; dst = wb + j * 8; }
  const uint4 a = *reinterpret_cast<const uint4*>(src);
  const uint4 bq = *reinterpret_cast<const uint4*>(src + 4);
  uint4 o;
  o.x = PERM_HI2(a.y, a.x);  o.y = PERM_HI2(a.w, a.z);
  o.z = PERM_HI2(bq.y, bq.x); o.w = PERM_HI2(bq.w, bq.z);
  *reinterpret_cast<uint4*>(dst) = o;
}

__global__ __launch_bounds__(256, 2)
void gemm_kernel(const ushort* __restrict__ xb, const ushort* __restrict__ wb,
                 const float* __restrict__ bias, float* __restrict__ out,
                 uint* __restrict__ tickets) {
  // 2-stage ring: exactly 64 KiB static LDS (the per-block max).
  __shared__ __align__(16) ushort As[2][BM * BK];   // 16 KiB / stage
  __shared__ __align__(16) ushort Bs[2][BN * BK];   // 16 KiB / stage

  // XCD swizzle: xcd = b&7; the 4 nt-blocks of one (mt,ks) group share an XCD
  // (x slab 128x1024 bf16 = 256 KiB fetched once per XCD L2).
  const int b    = blockIdx.x;                // 512 blocks
  const int xcd  = b & 7;
  const int slot = b >> 3;                    // 0..63
  const int nt   = slot & 3;                  // 0..3
  const int g    = (slot >> 2) * 8 + xcd;     // 0..127
  const int mt   = g >> 2;                    // 0..31
  const int ks   = g & 2 ? (g & 3) : (g & 3); // 0..3
  const int tid  = threadIdx.x;
  const int wv   = tid >> 6;
  const int lane = tid & 63;

  // DMA staging: per matrix, tile = 128 rows x 64 bf16 = 1024 16B-chunks
  // (8 chunks/row). LDS chunk c holds global chunk ((c&7) ^ (row&7)) of
  // row (c>>3) -- linear LDS dest, pre-swizzled global source.
  int goff[4], lloc[4];
#pragma unroll
  for (int j = 0; j < 4; ++j) {
    const int c  = (wv * 4 + j) * 64 + lane;
    const int r  = c >> 3;
    const int gs = (c & 7) ^ (r & 7);
    goff[j] = r * K + gs * 8;
    lloc[j] = (wv * 4 + j) * 512;   // wave-uniform LDS base (ushorts)
  }

  const ushort* xT = xb + (size_t)(mt * BM) * K + ks * KSPL;
  const ushort* wT = wb + (size_t)(nt * BN) * K + ks * KSPL;

  auto issue = [&](int tile, int stg) {
    const int ko = tile * BK;
#pragma unroll
    for (int j = 0; j < 4; ++j) async16(xT + ko + goff[j], &As[stg][lloc[j]]);
#pragma unroll
    for (int j = 0; j < 4; ++j) async16(wT + ko + goff[j], &Bs[stg][lloc[j]]);
  };

  const int wm = (wv & 1) * 64;
  const int wn = (wv >> 1) * 64;
  const int lr = lane & 15;
  const int lq = lane >> 4;

  f4 acc[4][4] = {};

  // prologue: tiles 0,1 into stages 0,1 (8 DMAs/wave each)
  issue(0, 0);
  issue(1, 1);

  int st = 0;
  for (int kk = 0; kk < NITER; ++kk) {
    // tile kk's 8 DMAs done; tile kk+1's 8 stay in flight across the barrier
    if (kk + 1 < NITER) __builtin_amdgcn_s_waitcnt(WAITCNT_VM8);
    else                __builtin_amdgcn_s_waitcnt(WAITCNT_VM0);
    __builtin_amdgcn_s_barrier();          // publish tile kk to all waves
    asm volatile("" ::: "memory");

    const ushort* aT = As[st];
    const ushort* bT = Bs[st];
#pragma unroll
    for (int t = 0; t < 2; ++t) {
      const int sc = ((t * 4 + lq) ^ (lr & 7)) * 8;
      bf8 af[4], bfv[4];
#pragma unroll
      for (int mf = 0; mf < 4; ++mf)
        af[mf] = *reinterpret_cast<const bf8*>(&aT[(wm + mf * 16 + lr) * BK + sc]);
#pragma unroll
      for (int nf = 0; nf < 4; ++nf)
        bfv[nf] = *reinterpret_cast<const bf8*>(&bT[(wn + nf * 16 + lr) * BK + sc]);
#pragma unroll
      for (int mf = 0; mf < 4; ++mf)
#pragma unroll
        for (int nf = 0; nf < 4; ++nf)
          acc[mf][nf] = __builtin_amdgcn_mfma_f32_16x16x32_bf16(af[mf], bfv[nf], acc[mf][nf], 0, 0, 0);
    }
    asm volatile("" ::: "memory");
    __builtin_amdgcn_s_barrier();          // all waves done READING stage st
    asm volatile("" ::: "memory");
    if (kk + 2 < NITER) issue(kk + 2, st); // safe: stage st now reusable
    st ^= 1;
  }

  // ---- split-K epilogue ------------------------------------------------
  // 1) store fp32 partial into output replica slot #ks of this tile:
  //    cols [nt*128 + ks*512, +128). C-frag layout: col=lane&15,
  //    row=(lane>>4)*4+reg (dtype-independent, verified m89/m91).
  float* pbase = out + (size_t)(mt * BM) * OUTF + nt * BN + ks * NS;
#pragma unroll
  for (int mf = 0; mf < 4; ++mf)
#pragma unroll
    for (int nf = 0; nf < 4; ++nf)
#pragma unroll
      for (int r = 0; r < 4; ++r)
        pbase[(size_t)(wm + mf * 16 + lq * 4 + r) * OUTF + wn + nf * 16 + lr] =
            acc[mf][nf][r];

  // 2) ticket: __syncthreads drains vmcnt(0) (stores committed to L2),
  //    release fence flushes L2 device-wide, then device-scope bump.
  __syncthreads();
  uint* s_oldp = reinterpret_cast<uint*>(&As[0][0]);  // K-loop LDS is dead
  if (tid == 0) {
    __threadfence();
    *s_oldp = __hip_atomic_fetch_add(&tickets[mt * NT + nt], 1u,
                                     __ATOMIC_ACQ_REL, __HIP_MEMORY_SCOPE_AGENT);
  }
  __syncthreads();
  if (*s_oldp != SPLITS - 1) return;       // losers exit

  // 3) winner (last split to finish): combine 4 partial slots + bias,
  //    broadcast to all 8 replica slots. Reads are L2/L3-warm float4.
  if (tid == 0) __threadfence();           // acquire: invalidate stale lines
  __syncthreads();

  const int c4 = tid & 31;                 // float4 column within 128-col tile
  const int rg = tid >> 5;                 // 8 row-groups; 16 rows/thread
  const float4* bias4 = reinterpret_cast<const float4*>(bias);
  float4 bb[8];
#pragma unroll
  for (int rep = 0; rep < 8; ++rep)
    bb[rep] = bias4[rep * 128 + nt * 32 + c4];

  float* obase = out + (size_t)(mt * BM) * OUTF + nt * BN;
#pragma unroll 4
  for (int rr = 0; rr < 16; ++rr) {
    const int row = rg + rr * 8;
    float* orow = obase + (size_t)row * OUTF;
    float sx = 0.f, sy = 0.f, sz = 0.f, sw = 0.f;
#pragma unroll
    for (int sp = 0; sp < SPLITS; ++sp) {
      const float4 p = *reinterpret_cast<const float4*>(orow + sp * NS + c4 * 4);
      sx += p.x; sy += p.y; sz += p.z; sw += p.w;
    }
#pragma unroll
    for (int rep = 0; rep < 8; ++rep) {
      float4 o;
      o.x = sx + bb[rep].x; o.y = sy + bb[rep].y;
      o.z = sz + bb[rep].z; o.w = sw + bb[rep].w;
      *reinterpret_cast<float4*>(orow + rep * NS + c4 * 4) = o;
    }
  }
}

extern "C" void kernel_launch(void* const* d_in, const int* in_sizes, int n_in,
                              void* d_out, int out_size, void* d_ws, size_t ws_size,
                              hipStream_t stream) {
  (void)in_sizes; (void)n_in; (void)out_size; (void)ws_size;
  const float* x    = (const float*)d_in[0];
  const float* w    = (const float*)d_in[1];
  const float* bias = (const float*)d_in[2];
  float* out = (float*)d_out;

  ushort* xb = (ushort*)d_ws;                       // 32 MiB bf16 x
  ushort* wb = xb + (size_t)M * K;                  // 4 MiB bf16 W
  uint* tickets = (uint*)(wb + (size_t)NS * K);     // 512 B (ws >= 36 MiB + 512 B)

  constexpr int conv_blocks = (int)(((size_t)M * K / 8 + (size_t)NS * K / 8) / 256); // 9216
  convert_kernel<<<dim3(conv_blocks), dim3(256), 0, stream>>>(x, w, xb, wb, tickets);
  gemm_kernel<<<dim3(MT * NT * SPLITS), dim3(256), 0, stream>>>(xb, wb, bias, out, tickets);
}

// Round 2
// 174.906 us; speedup vs baseline: 1.3532x; 1.3532x over previous
//
#include <hip/hip_runtime.h>
#include <hip/hip_bf16.h>

// y[b, c] = (sum_k x[b,k] * W[c % 512, k]) + bias[c]
// R7: revert to the proven R5 GEMM structure (64x64 tiles, 3-stage LDS ring,
// counted s_waitcnt, XCD swizzle, LDS-transpose epilogue -> 8 replica copies)
// and FUSE the x fp32->bf16 conversion into the GEMM:
//   - A is staged as raw fp32 via global_load_lds (DMA path kept; 16 KB/stage),
//     converted to bf16 in-register after ds_read (2x ds_read_b128 + 4 v_perm
//     per fragment, same truncation numerics as the old convert kernel).
//   - B (W) keeps the tiny standalone convert (12 MB traffic, ~3 us) so the
//     proven bf16 B path is byte-identical to R5.
//   - A DMA swizzle generalized to 16-chunk fp32 rows: LDS chunk c holds
//     global chunk (c&15)^(r&15); reads land 2-way bank-aliased (free).
//   - vmcnt counting: 6 DMAs/wave/tile (4 A + 2 B) -> wait vmcnt<=6 drains
//     exactly tile kk while tile kk+1 stays in flight (depth-2 prefetch).
// Net vs R5: convert traffic 108 MB -> 12 MB; gemm fetch 33 -> ~70 MB fp32
// (x slab read once per XCD); one big dispatch removed.
// Split-K (R6) abandoned: cross-XCD partial combine tail cost ~100 us.

typedef __bf16 bf8 __attribute__((ext_vector_type(8)));
typedef float f4 __attribute__((ext_vector_type(4)));
typedef unsigned int uint;
typedef unsigned short ushort;

constexpr int M = 4096;
constexpr int K = 4096;
constexpr int NS = 512;
constexpr int OUTF = 4096;
constexpr int BM = 64, BN = 64, BK = 64;
constexpr int NITER = K / BK;    // 64
constexpr int SSTR = 68;         // epilogue scratch stride (floats)

#define PERM_HI2(hi, lo) __builtin_amdgcn_perm((hi), (lo), 0x07060302u)
// s_waitcnt imm: vmcnt[3:0]|expcnt[6:4]|lgkmcnt[11:8]|vmcnt[15:14]
#define WAITCNT_VM6 0xF76   // vmcnt<=6 (tile kk drained, tile kk+1 in flight)
#define WAITCNT_VM0 0xF70   // vmcnt<=0

__device__ __forceinline__ void async16(const void* g, void* l) {
  __builtin_amdgcn_global_load_lds(
      (const __attribute__((address_space(1))) void*)g,
      (__attribute__((address_space(3))) void*)l, 16, 0, 0);
}

// W only: fp32 -> bf16 (truncate), 8 elems/thread. 512*4096/8/256 = 1024 blocks.
__global__ __launch_bounds__(256)
void convert_w(const float* __restrict__ w, ushort* __restrict__ wb) {
  const size_t i = (size_t)blockIdx.x * 256 + threadIdx.x;
  const float* src = w + i * 8;
  ushort* dst = wb + i * 8;
  const uint4 a = *reinterpret_cast<const uint4*>(src);
  const uint4 b = *reinterpret_cast<const uint4*>(src + 4);
  uint4 o;
  o.x = PERM_HI2(a.y, a.x); o.y = PERM_HI2(a.w, a.z);
  o.z = PERM_HI2(b.y, b.x); o.w = PERM_HI2(b.w, b.z);
  *reinterpret_cast<uint4*>(dst) = o;
}

__global__ __launch_bounds__(256, 2)
void gemm_kernel(const float* __restrict__ x, const ushort* __restrict__ wb,
                 const float* __restrict__ bias, float* __restrict__ out) {
  __shared__ __align__(16) float  As[3][BM * BK];   // fp32 x tiles, 16 KB/stage
  __shared__ __align__(16) ushort Bs[3][BN * BK];   // bf16 W tiles,  8 KB/stage
  // total 72 KB -> 2 blocks/CU (same residency as R5's 48 KB at grid 2/CU)

  // XCD swizzle: blockIdx&7 == mt&7 -> all 8 nt-blocks of an x-slab share an
  // XCD; the 1 MB fp32 slab is fetched from HBM once per XCD L2.
  const int b  = blockIdx.x;                  // 512 blocks
  const int mt = ((b >> 6) << 3) | (b & 7);   // 0..63
  const int nt = (b >> 3) & 7;                // 0..7

  const int tid  = threadIdx.x;
  const int wv   = tid >> 6;
  const int lane = tid & 63;

  // A DMA: tile = 64 rows x 64 f32 = 1024 16B-chunks (16/row); 4 insts/wave.
  // LDS chunk c holds global chunk ((c&15) ^ (r&15)) of row (c>>4).
  int goffA[4], llocA[4];
#pragma unroll
  for (int j = 0; j < 4; ++j) {
    const int c = (wv * 4 + j) * 64 + lane;
    const int r = c >> 4;
    const int g = (c & 15) ^ (r & 15);
    goffA[j] = r * K + g * 4;       // float units
    llocA[j] = (wv * 4 + j) * 256;  // float units (1 KB per wave-inst)
  }
  // B DMA: tile = 64 rows x 64 bf16 = 512 chunks (8/row); 2 insts/wave (R5).
  int goffB[2], llocB[2];
#pragma unroll
  for (int j = 0; j < 2; ++j) {
    const int c = (wv * 2 + j) * 64 + lane;
    const int r = c >> 3;
    const int g = (c & 7) ^ (r & 7);
    goffB[j] = r * K + g * 8;       // ushort units
    llocB[j] = (wv * 2 + j) * 512;
  }

  const float*  xT = x  + (size_t)(mt * BM) * K;
  const ushort* wT = wb + (size_t)(nt * BN) * K;

  const int wm = (wv & 1) * 32;
  const int wn = (wv >> 1) * 32;
  const int lr = lane & 15;
  const int lq = lane >> 4;

  f4 acc[2][2] = {};

  auto issue = [&](int tile, int stage) {
    const int ko = tile * BK;
#pragma unroll
    for (int j = 0; j < 4; ++j)
      async16(xT + ko + goffA[j], &As[stage][llocA[j]]);
#pragma unroll
    for (int j = 0; j < 2; ++j)
      async16(wT + ko + goffB[j], &Bs[stage][llocB[j]]);
  };

  // prologue: tiles 0,1 into stages 0,1 (6 DMAs/wave each)
  issue(0, 0);
  issue(1, 1);

  int st = 0;                 // stage of current tile kk
  for (int kk = 0; kk < NITER; ++kk) {
    // drain this wave's tile-kk DMAs (oldest 6); tile kk+1's 6 stay in flight
    if (kk + 1 < NITER) __builtin_amdgcn_s_waitcnt(WAITCNT_VM6);
    else                __builtin_amdgcn_s_waitcnt(WAITCNT_VM0);
    __builtin_amdgcn_s_barrier();    // publish tile kk; all waves done reading stage (kk-1)%3
    asm volatile("" ::: "memory");

    // issue tile kk+2 into stage (kk+2)%3 == (kk-1)%3 (safe: post-barrier)
    if (kk + 2 < NITER) {
      int st2 = st + 2; if (st2 >= 3) st2 -= 3;
      issue(kk + 2, st2);
    }

    const float*  aT = As[st];
    const ushort* bT = Bs[st];
#pragma unroll
    for (int t = 0; t < 2; ++t) {
      bf8 af[2], bfv[2];
#pragma unroll
      for (int mf = 0; mf < 2; ++mf) {
        // lane wants global f32 chunks q0,q0+1 of row: q0 = (t*4+lq)*2.
        // DMA swizzle: LDS chunk = global ^ (row&15); row&15 == lr here.
        const int row = wm + mf * 16 + lr;
        const int ca  = ((t * 4 + lq) * 2) ^ lr;
        const f4 a0 = *reinterpret_cast<const f4*>(&aT[row * BK + ca * 4]);
        const f4 a1 = *reinterpret_cast<const f4*>(&aT[row * BK + (ca ^ 1) * 4]);
        const uint* u0 = reinterpret_cast<const uint*>(&a0);
        const uint* u1 = reinterpret_cast<const uint*>(&a1);
        uint4 p;
        p.x = PERM_HI2(u0[1], u0[0]); p.y = PERM_HI2(u0[3], u0[2]);
        p.z = PERM_HI2(u1[1], u1[0]); p.w = PERM_HI2(u1[3], u1[2]);
        af[mf] = __builtin_bit_cast(bf8, p);
      }
      const int sc = ((t * 4 + lq) ^ (lr & 7)) * 8;
#pragma unroll
      for (int nf = 0; nf < 2; ++nf)
        bfv[nf] = *reinterpret_cast<const bf8*>(&bT[(wn + nf * 16 + lr) * BK + sc]);
#pragma unroll
      for (int mf = 0; mf < 2; ++mf)
#pragma unroll
        for (int nf = 0; nf < 2; ++nf)
          acc[mf][nf] = __builtin_amdgcn_mfma_f32_16x16x32_bf16(af[mf], bfv[nf], acc[mf][nf], 0, 0, 0);
    }
    asm volatile("" ::: "memory");

    if (++st >= 3) st = 0;
  }

  // ---- epilogue: LDS transpose -> float4 stores of acc+bias into all 8
  // column copies (unchanged from R5). As is 48 KB fp32 >= 64*68*4 B.
  __syncthreads();
  float* scr = &As[0][0];
#pragma unroll
  for (int mf = 0; mf < 2; ++mf)
#pragma unroll
    for (int nf = 0; nf < 2; ++nf)
#pragma unroll
      for (int r = 0; r < 4; ++r)
        scr[(wm + mf * 16 + lq * 4 + r) * SSTR + wn + nf * 16 + lr] = acc[mf][nf][r];
  __syncthreads();

  const int c4 = tid & 15;          // float4 column within tile
  const int r0 = (tid >> 4) * 4;    // 4 rows per thread
  const float4* bias4 = reinterpret_cast<const float4*>(bias);
  float4 bb[8];
#pragma unroll
  for (int rep = 0; rep < 8; ++rep)
    bb[rep] = bias4[rep * 128 + nt * 16 + c4];

#pragma unroll
  for (int rr = 0; rr < 4; ++rr) {
    const int row = r0 + rr;
    const float4 v = *reinterpret_cast<const float4*>(&scr[row * SSTR + c4 * 4]);
    float* orow = out + (size_t)(mt * BM + row) * OUTF + nt * BN + c4 * 4;
#pragma unroll
    for (int rep = 0; rep < 8; ++rep) {
      float4 o;
      o.x = v.x + bb[rep].x; o.y = v.y + bb[rep].y;
      o.z = v.z + bb[rep].z; o.w = v.w + bb[rep].w;
      *reinterpret_cast<float4*>(orow + rep * NS) = o;
    }
  }
}

extern "C" void kernel_launch(void* const* d_in, const int* in_sizes, int n_in,
                              void* d_out, int out_size, void* d_ws, size_t ws_size,
                              hipStream_t stream) {
  (void)in_sizes; (void)n_in; (void)out_size; (void)ws_size;
  const float* x    = (const float*)d_in[0];
  const float* w    = (const float*)d_in[1];
  const float* bias = (const float*)d_in[2];
  float* out = (float*)d_out;

  ushort* wb = (ushort*)d_ws;       // 4 MB bf16 W (ws >= 4 MB)

  constexpr int convw_blocks = (int)((size_t)NS * K / 8 / 256);  // 1024
  convert_w<<<dim3(convw_blocks), dim3(256), 0, stream>>>(w, wb);
  gemm_kernel<<<dim3(64 * 8), dim3(256), 0, stream>>>(x, wb, bias, out);
}

// Round 3
// 161.645 us; speedup vs baseline: 1.4642x; 1.0820x over previous
//
#include <hip/hip_runtime.h>
#include <hip/hip_bf16.h>

// y[b, c] = (sum_k x[b,k] * W[c % 512, k]) + bias[c]
// R8: R5 pipeline (convert x,W -> bf16; 64x64 tiles, 3-stage LDS ring, counted
// vmcnt, XCD swizzle) with the K-loop restructured as SPLIT-K WITHIN THE BLOCK:
//   - model (validated on R5 vs R7: dur proportional to LDS bytes, 96 KB->58.5us,
//     144 KB->87.5us): the K-loop is LDS-traffic-bound at ~46 B/cy/CU.
//   - R5's 4 waves at wave-tile 32x32 read every staged byte twice (amp 2.0).
//     R8: each wave computes the FULL 64x64 for its own K=16 slice of each
//     BK=64 tile via mfma_f32_32x32x16_bf16: 4 ds_read_b128 + 4 MFMA per
//     wave-iter, read amplification exactly 1.0 -> 64 KB/CU-iter (was 96).
//   - DMA staging, swizzle, ring, barriers, vmcnt counting: byte-identical R5.
//   - Epilogue: 4 rounds over 16-row quarters; waves dump their K-partial regs
//     to LDS scratch (4 copies), 256 threads sum 4 copies + bias, float4-store
//     into all 8 column replicas. All acc indices compile-time (rule #20).
// A/B frag layout (32x32x16): row/col = lane&31, k = (lane>>5)*8 + j.
// C/D layout: col = lane&31, row = (reg&3) + 8*(reg>>2) + 4*(lane>>5)  [m74].

typedef __bf16 bf8 __attribute__((ext_vector_type(8)));
typedef float f16v __attribute__((ext_vector_type(16)));
typedef unsigned int uint;
typedef unsigned short ushort;

constexpr int M = 4096;
constexpr int K = 4096;
constexpr int NS = 512;
constexpr int OUTF = 4096;
constexpr int BM = 64, BN = 64, BK = 64;
constexpr int NITER = K / BK;    // 64
constexpr int SSTR = 68;         // scratch row stride (floats), 272 B keeps 16B align
constexpr int WSTR = 16 * SSTR;  // scratch per-wave-copy stride (floats)

#define PERM_HI2(hi, lo) __builtin_amdgcn_perm((hi), (lo), 0x07060302u)
// s_waitcnt imm: vmcnt[3:0]|expcnt[6:4]|lgkmcnt[11:8]|vmcnt[15:14]
#define WAITCNT_VM4 0xF74   // vmcnt<=4 (tile kk drained, tile kk+1 in flight)
#define WAITCNT_VM0 0xF70   // vmcnt<=0

__device__ __forceinline__ void async16(const ushort* g, ushort* l) {
  __builtin_amdgcn_global_load_lds(
      (const __attribute__((address_space(1))) void*)g,
      (__attribute__((address_space(3))) void*)l, 16, 0, 0);
}

// fp32 -> bf16 (truncate), 8 elems/thread; covers x then W exactly (R0 version).
__global__ __launch_bounds__(256)
void convert_kernel(const float* __restrict__ x, const float* __restrict__ w,
                    ushort* __restrict__ xb, ushort* __restrict__ wb) {
  const size_t i = (size_t)blockIdx.x * 256 + threadIdx.x;
  constexpr size_t NX = (size_t)M * K / 8;
  const float* src;
  ushort* dst;
  if (i < NX) { src = x + i * 8; dst = xb + i * 8; }
  else        { const size_t j = i - NX; src = w + j * 8; dst = wb + j * 8; }
  const uint4 a = *reinterpret_cast<const uint4*>(src);
  const uint4 b = *reinterpret_cast<const uint4*>(src + 4);
  uint4 o;
  o.x = PERM_HI2(a.y, a.x); o.y = PERM_HI2(a.w, a.z);
  o.z = PERM_HI2(b.y, b.x); o.w = PERM_HI2(b.w, b.z);
  *reinterpret_cast<uint4*>(dst) = o;
}

__global__ __launch_bounds__(256, 2)
void gemm_kernel(const ushort* __restrict__ xb, const ushort* __restrict__ wb,
                 const float* __restrict__ bias, float* __restrict__ out) {
  __shared__ __align__(16) ushort As[3][BM * BK];   // 3-stage ring, 8 KB/stage
  __shared__ __align__(16) ushort Bs[3][BN * BK];

  // XCD swizzle: blockIdx&7 == mt&7 -> all 8 nt-blocks of an x-slab share an XCD.
  const int b  = blockIdx.x;                  // 512 blocks
  const int mt = ((b >> 6) << 3) | (b & 7);   // 0..63
  const int nt = (b >> 3) & 7;                // 0..7

  const int tid  = threadIdx.x;
  const int wv   = tid >> 6;
  const int lane = tid & 63;

  // DMA staging (identical to R5): tile = 64 rows x 64 bf16 = 512 16B-chunks.
  // LDS chunk c holds global chunk ((c&7) ^ (row&7)) of row (c>>3).
  int goff[2], lloc[2];
#pragma unroll
  for (int j = 0; j < 2; ++j) {
    const int c = (wv * 2 + j) * 64 + lane;
    const int r = c >> 3;
    const int g = (c & 7) ^ (r & 7);
    goff[j] = r * K + g * 8;
    lloc[j] = (wv * 2 + j) * 512;
  }

  const ushort* xT = xb + (size_t)(mt * BM) * K;
  const ushort* wT = wb + (size_t)(nt * BN) * K;

  auto issue = [&](int tile, int stage) {
    const int ko = tile * BK;
#pragma unroll
    for (int j = 0; j < 2; ++j) {
      async16(xT + ko + goff[j], &As[stage][lloc[j]]);
      async16(wT + ko + goff[j], &Bs[stage][lloc[j]]);
    }
  };

  const int l31 = lane & 31;
  const int hi  = lane >> 5;
  // wave wv owns k-slice [wv*16, wv*16+16) of each BK=64 tile.
  // lane reads global k-chunk q = 2*wv + hi; LDS chunk = q ^ (row&7), row&7 = lane&7.
  const int coff = ((2 * wv + hi) ^ (lane & 7)) * 8;   // ushort offset within row

  f16v acc[2][2] = {};   // full 64x64 fp32 partial for this wave's k-slice

  // prologue: tiles 0,1 into stages 0,1 (4 DMAs/wave each)
  issue(0, 0);
  issue(1, 1);

  int st = 0;                 // stage of current tile kk
  for (int kk = 0; kk < NITER; ++kk) {
    // drain this wave's tile-kk DMAs (oldest 4); tile kk+1's 4 stay in flight
    if (kk + 1 < NITER) __builtin_amdgcn_s_waitcnt(WAITCNT_VM4);
    else                __builtin_amdgcn_s_waitcnt(WAITCNT_VM0);
    __builtin_amdgcn_s_barrier();    // publish tile kk; all waves done reading stage (kk-1)%3
    asm volatile("" ::: "memory");

    // issue tile kk+2 into stage (kk+2)%3 == (kk-1)%3 (safe: post-barrier)
    if (kk + 2 < NITER) {
      int st2 = st + 2; if (st2 >= 3) st2 -= 3;
      issue(kk + 2, st2);
    }

    const ushort* aT = As[st];
    const ushort* bT = Bs[st];
    const bf8 a0 = *reinterpret_cast<const bf8*>(&aT[(l31)      * BK + coff]);
    const bf8 a1 = *reinterpret_cast<const bf8*>(&aT[(32 + l31) * BK + coff]);
    const bf8 b0 = *reinterpret_cast<const bf8*>(&bT[(l31)      * BK + coff]);
    const bf8 b1 = *reinterpret_cast<const bf8*>(&bT[(32 + l31) * BK + coff]);
    acc[0][0] = __builtin_amdgcn_mfma_f32_32x32x16_bf16(a0, b0, acc[0][0], 0, 0, 0);
    acc[0][1] = __builtin_amdgcn_mfma_f32_32x32x16_bf16(a0, b1, acc[0][1], 0, 0, 0);
    acc[1][0] = __builtin_amdgcn_mfma_f32_32x32x16_bf16(a1, b0, acc[1][0], 0, 0, 0);
    acc[1][1] = __builtin_amdgcn_mfma_f32_32x32x16_bf16(a1, b1, acc[1][1], 0, 0, 0);
    asm volatile("" ::: "memory");

    if (++st >= 3) st = 0;
  }

  // ---- epilogue: reduce 4 per-wave K-partials, add bias, store 8 replicas ----
  __syncthreads();                                   // ring LDS now dead
  float* scr = reinterpret_cast<float*>(&As[0][0]);  // 4*WSTR*4 = 17408 B <= 24 KB

  const int c4  = tid & 15;          // float4 column within 64-col tile
  const int r16 = tid >> 4;          // row within 16-row quarter
  const float4* bias4 = reinterpret_cast<const float4*>(bias);
  float4 bb[8];
#pragma unroll
  for (int rep = 0; rep < 8; ++rep)
    bb[rep] = bias4[rep * 128 + nt * 16 + c4];

#pragma unroll
  for (int rq = 0; rq < 4; ++rq) {                   // output rows [rq*16, +16)
    const int tm = rq >> 1, half = rq & 1;
    // dump this wave's partial for the quarter: regs 8*half..+8 of acc[tm][*]
#pragma unroll
    for (int tn = 0; tn < 2; ++tn)
#pragma unroll
      for (int j = 0; j < 8; ++j) {
        const int row16 = (j & 3) + 8 * (j >> 2) + 4 * hi;   // C/D row formula
        scr[wv * WSTR + row16 * SSTR + tn * 32 + l31] = acc[tm][tn][8 * half + j];
      }
    __syncthreads();
    // combine 4 wave-copies + bias -> all 8 column replicas
    float4 s;
    {
      const float4 p0 = *reinterpret_cast<const float4*>(&scr[0 * WSTR + r16 * SSTR + c4 * 4]);
      const float4 p1 = *reinterpret_cast<const float4*>(&scr[1 * WSTR + r16 * SSTR + c4 * 4]);
      const float4 p2 = *reinterpret_cast<const float4*>(&scr[2 * WSTR + r16 * SSTR + c4 * 4]);
      const float4 p3 = *reinterpret_cast<const float4*>(&scr[3 * WSTR + r16 * SSTR + c4 * 4]);
      s.x = (p0.x + p1.x) + (p2.x + p3.x);
      s.y = (p0.y + p1.y) + (p2.y + p3.y);
      s.z = (p0.z + p1.z) + (p2.z + p3.z);
      s.w = (p0.w + p1.w) + (p2.w + p3.w);
    }
    float* orow = out + (size_t)(mt * BM + rq * 16 + r16) * OUTF + nt * BN + c4 * 4;
#pragma unroll
    for (int rep = 0; rep < 8; ++rep) {
      float4 o;
      o.x = s.x + bb[rep].x; o.y = s.y + bb[rep].y;
      o.z = s.z + bb[rep].z; o.w = s.w + bb[rep].w;
      *reinterpret_cast<float4*>(orow + rep * NS) = o;
    }
    __syncthreads();                                 // scratch reused next round
  }
}

extern "C" void kernel_launch(void* const* d_in, const int* in_sizes, int n_in,
                              void* d_out, int out_size, void* d_ws, size_t ws_size,
                              hipStream_t stream) {
  (void)in_sizes; (void)n_in; (void)out_size; (void)ws_size;
  const float* x    = (const float*)d_in[0];
  const float* w    = (const float*)d_in[1];
  const float* bias = (const float*)d_in[2];
  float* out = (float*)d_out;

  ushort* xb = (ushort*)d_ws;                       // 32 MB bf16 x
  ushort* wb = (ushort*)d_ws + (size_t)M * K;       // 4 MB bf16 W (ws >= 36 MB)

  constexpr int conv_blocks = (int)(((size_t)M * K / 8 + (size_t)NS * K / 8) / 256); // 9216
  convert_kernel<<<dim3(conv_blocks), dim3(256), 0, stream>>>(x, w, xb, wb);
  gemm_kernel<<<dim3(64 * 8), dim3(256), 0, stream>>>(xb, wb, bias, out);
}